// Round 9
// baseline (469.272 us; speedup 1.0000x reference)
//
#include <hip/hip_runtime.h>
#include <hip/hip_bf16.h>
#include <math.h>

#define NN 50000
#define NE 600000
#define MPAD 50048      // 3128*16
#define NW16 (MPAD / 16)
#define DIM 128
#define HID 256
#define NB 49           // ceil(NN/1024)
#define HIST_BLOCKS ((NE + 255) / 256)
#define CAST_BLOCKS ((4 * DIM * HID) / 256)
#define EPS_MSG 1e-7f
#define EPS_NORM 1e-5f

typedef __attribute__((ext_vector_type(8))) short short8v;
typedef __attribute__((ext_vector_type(8))) unsigned short ushort8v;
typedef __attribute__((ext_vector_type(4))) float f32x4;

__device__ inline ushort f2bf(float f) {
    union { float f; unsigned u; } v; v.f = f;
    unsigned r = v.u + 0x7FFF + ((v.u >> 16) & 1);
    return (ushort)(r >> 16);
}
__device__ inline float bf2f(ushort u) {
    union { unsigned u; float f; } v; v.u = (unsigned)u << 16; return v.f;
}

// ---- fused setup: blocks [0,64) xstats | [64,64+HIST) hist | rest weight cast+T ----
__global__ __launch_bounds__(256) void k_setup(const float* __restrict__ x,
                                               const int* __restrict__ dst,
                                               const float* __restrict__ W1,
                                               const float* __restrict__ W2,
                                               float* __restrict__ xs,
                                               int* __restrict__ deg,
                                               ushort* __restrict__ W1t,
                                               ushort* __restrict__ W2t) {
    int b = blockIdx.x;
    if (b < 64) {
        int lane = threadIdx.x & 63;
        float s = 0.f, q = 0.f;
        for (int i = b * 256 + threadIdx.x; i < NN; i += 64 * 256) {
            float v = x[i];
            s += v; q += v * v;
        }
        #pragma unroll
        for (int off = 32; off >= 1; off >>= 1) {
            s += __shfl_xor(s, off, 64);
            q += __shfl_xor(q, off, 64);
        }
        if (lane == 0) { atomicAdd(&xs[0], s); atomicAdd(&xs[1], q); }
    } else if (b < 64 + HIST_BLOCKS) {
        int i = (b - 64) * 256 + threadIdx.x;
        if (i < NE) atomicAdd(&deg[dst[i]], 1);
    } else {
        const int chunk = DIM * HID;
        int i = (b - 64 - HIST_BLOCKS) * 256 + threadIdx.x;
        int w = i / chunk;
        int j = i - w * chunk;
        if (w < 2) {
            int r = j / HID, c = j - r * HID;
            W1t[(size_t)w * chunk + (size_t)c * DIM + r] = f2bf(W1[(size_t)w * chunk + j]);
        } else {
            int l = w - 2;
            int r = j / DIM, c = j - r * DIM;
            W2t[(size_t)l * chunk + (size_t)c * HID + r] = f2bf(W2[(size_t)l * chunk + j]);
        }
    }
}

// ------- layer-0 hn (bf16): BN params in closed form (h = x*Wn + bnb is rank-1) -------
__global__ void k_hn0(const float* __restrict__ x, const float* __restrict__ xs,
                      const float* __restrict__ Wn, const float* __restrict__ bnb,
                      const float* __restrict__ gamma, const float* __restrict__ beta,
                      ushort* __restrict__ hn, int total4) {
    int i = blockIdx.x * blockDim.x + threadIdx.x;
    if (i >= total4) return;
    int d4 = (i & 31) * 4;
    int n = i >> 5;
    float mx = xs[0] * (1.f / NN);
    float vx = xs[1] * (1.f / NN) - mx * mx;
    float xv = x[n];
    float4 w = *(const float4*)(Wn + d4);
    float4 b = *(const float4*)(bnb + d4);
    float4 g = *(const float4*)(gamma + d4);
    float4 bt = *(const float4*)(beta + d4);
    ushort4 o;
    {
        float mu = fmaf(mx, w.x, b.x), sc = rsqrtf(vx * w.x * w.x + EPS_NORM) * g.x;
        o.x = f2bf(fmaxf(fmaf(fmaf(xv, w.x, b.x) - mu, sc, bt.x), 0.f));
    }
    {
        float mu = fmaf(mx, w.y, b.y), sc = rsqrtf(vx * w.y * w.y + EPS_NORM) * g.y;
        o.y = f2bf(fmaxf(fmaf(fmaf(xv, w.y, b.y) - mu, sc, bt.y), 0.f));
    }
    {
        float mu = fmaf(mx, w.z, b.z), sc = rsqrtf(vx * w.z * w.z + EPS_NORM) * g.z;
        o.z = f2bf(fmaxf(fmaf(fmaf(xv, w.z, b.z) - mu, sc, bt.z), 0.f));
    }
    {
        float mu = fmaf(mx, w.w, b.w), sc = rsqrtf(vx * w.w * w.w + EPS_NORM) * g.w;
        o.w = f2bf(fmaxf(fmaf(fmaf(xv, w.w, b.w) - mu, sc, bt.w), 0.f));
    }
    *(ushort4*)(hn + (size_t)n * DIM + d4) = o;
}

// ---------------- CSR build (multi-block scan) ----------------
__global__ __launch_bounds__(256) void k_scanA(const int* __restrict__ deg,
                                               int* __restrict__ partials, int n) {
    __shared__ int ws[4];
    int b = blockIdx.x;
    int t = threadIdx.x;
    int s = 0;
    #pragma unroll
    for (int i = 0; i < 4; ++i) {
        int idx = b * 1024 + t + i * 256;
        s += (idx < n) ? deg[idx] : 0;
    }
    #pragma unroll
    for (int off = 32; off >= 1; off >>= 1) s += __shfl_xor(s, off, 64);
    if ((t & 63) == 0) ws[t >> 6] = s;
    __syncthreads();
    if (t == 0) partials[b] = ws[0] + ws[1] + ws[2] + ws[3];
}

__global__ __launch_bounds__(64) void k_scanB(const int* __restrict__ partials,
                                              int* __restrict__ base,
                                              int* __restrict__ row_off) {
    int t = threadIdx.x;
    int v = (t < NB) ? partials[t] : 0;
    int x = v;
    #pragma unroll
    for (int off = 1; off < 64; off <<= 1) {
        int y = __shfl_up(x, off, 64);
        if (t >= off) x += y;
    }
    if (t < NB) base[t] = x - v;
    if (t == 0) row_off[NN] = NE;
}

__global__ __launch_bounds__(1024) void k_scanC(const int* __restrict__ deg,
                                                const int* __restrict__ base,
                                                int* __restrict__ row_off,
                                                int* __restrict__ cursor, int n) {
    __shared__ int wsum[16];
    int i = blockIdx.x * 1024 + threadIdx.x;
    int lane = threadIdx.x & 63;
    int wid = threadIdx.x >> 6;
    int v = (i < n) ? deg[i] : 0;
    int x = v;
    #pragma unroll
    for (int off = 1; off < 64; off <<= 1) {
        int y = __shfl_up(x, off, 64);
        if (lane >= off) x += y;
    }
    if (lane == 63) wsum[wid] = x;
    __syncthreads();
    if (wid == 0 && lane < 16) {
        int w = wsum[lane];
        #pragma unroll
        for (int off = 1; off < 16; off <<= 1) {
            int y = __shfl_up(w, off, 64);
            if (lane >= off) w += y;
        }
        wsum[lane] = w;
    }
    __syncthreads();
    int prev = (wid == 0) ? 0 : wsum[wid - 1];
    int excl = base[blockIdx.x] + prev + (x - v);
    if (i < n) { row_off[i] = excl; cursor[i] = excl; }
}

// scatter edge record {src, eid, ea_bits, 0} to CSR slot (one 16B store)
__global__ void k_scatter(const int* __restrict__ src, const int* __restrict__ dst,
                          const float* __restrict__ eattr, int* __restrict__ cursor,
                          int4* __restrict__ erec, int E) {
    int i = blockIdx.x * blockDim.x + threadIdx.x;
    if (i >= E) return;
    int d = dst[i];
    int pos = atomicAdd(&cursor[d], 1);
    erec[pos] = make_int4(src[i], i, __float_as_int(eattr[i]), 0);
}

// ------- BN column stats over h (fp32): grid-stride, per-thread accumulate -------
__global__ __launch_bounds__(256) void k_bn_stats(const float* __restrict__ h,
                                                  float* __restrict__ stats) {
    __shared__ float red[2][128];
    int d = threadIdx.x & 127;
    int rsub = threadIdx.x >> 7;
    float s = 0.f, q = 0.f;
    for (int r = blockIdx.x * 2 + rsub; r < NN; r += gridDim.x * 2) {
        float v = h[(size_t)r * DIM + d];
        s += v; q += v * v;
    }
    if (rsub == 0) { red[0][d] = s; red[1][d] = q; }
    __syncthreads();
    if (rsub == 1) {
        atomicAdd(&stats[d], s + red[0][d]);
        atomicAdd(&stats[DIM + d], q + red[1][d]);
    }
}

// ------- BN apply + ReLU -> bf16 hn (finalize fused per-thread from raw stats) -------
__global__ void k_bn_relu(const float* __restrict__ h, const float* __restrict__ stats,
                          const float* __restrict__ gamma, const float* __restrict__ beta,
                          ushort* __restrict__ hn, int total4) {
    int i = blockIdx.x * blockDim.x + threadIdx.x;
    if (i >= total4) return;
    int d4 = (i & 31) * 4;
    int n = i >> 5;
    float4 v = *(const float4*)(h + (size_t)n * DIM + d4);
    float4 s = *(const float4*)(stats + d4);
    float4 q = *(const float4*)(stats + DIM + d4);
    float4 g = *(const float4*)(gamma + d4);
    float4 bt = *(const float4*)(beta + d4);
    ushort4 o;
    {
        float mu = s.x * (1.f / NN), var = q.x * (1.f / NN) - mu * mu;
        float sc = rsqrtf(var + EPS_NORM) * g.x;
        o.x = f2bf(fmaxf(fmaf(v.x - mu, sc, bt.x), 0.f));
    }
    {
        float mu = s.y * (1.f / NN), var = q.y * (1.f / NN) - mu * mu;
        float sc = rsqrtf(var + EPS_NORM) * g.y;
        o.y = f2bf(fmaxf(fmaf(v.y - mu, sc, bt.y), 0.f));
    }
    {
        float mu = s.z * (1.f / NN), var = q.z * (1.f / NN) - mu * mu;
        float sc = rsqrtf(var + EPS_NORM) * g.z;
        o.z = f2bf(fmaxf(fmaf(v.z - mu, sc, bt.z), 0.f));
    }
    {
        float mu = s.w * (1.f / NN), var = q.w * (1.f / NN) - mu * mu;
        float sc = rsqrtf(var + EPS_NORM) * g.w;
        o.w = f2bf(fmaxf(fmaf(v.w - mu, sc, bt.w), 0.f));
    }
    *(ushort4*)(hn + (size_t)n * DIM + d4) = o;
}

// ------- GENConv softmax aggregation: wave per node, lane = 2 channels, unroll-8 -------
__global__ __launch_bounds__(256) void k_agg(const ushort* __restrict__ hn,
                                             const int4* __restrict__ erec,
                                             const int* __restrict__ row_off,
                                             const float* __restrict__ We,
                                             const float* __restrict__ be,
                                             const float* __restrict__ t_all, int l,
                                             ushort* __restrict__ ob, int N) {
    int n = blockIdx.x * 4 + (threadIdx.x >> 6);
    if (n >= N) return;
    int lane = threadIdx.x & 63;
    int d0 = lane * 2;
    float2 we = *(const float2*)(We + d0);
    float2 bd = *(const float2*)(be + d0);
    float t = t_all[l];
    int p0 = row_off[n], p1 = row_off[n + 1];
    int deg = p1 - p0;

    int mp = p0 + lane;
    int s_l = 0; float ea_l = 0.f;
    if (mp < p1) {
        int4 r = erec[mp];
        s_l = r.x; ea_l = __int_as_float(r.z);
    }

    float den0 = 0.f, num0 = 0.f, den1 = 0.f, num1 = 0.f;
    int kmax = deg < 64 ? deg : 64;
    int k = 0;
    for (; k + 8 <= kmax; k += 8) {
        int ss[8]; float ee[8]; uint hv[8];
        #pragma unroll
        for (int u = 0; u < 8; ++u) {
            ss[u] = __shfl(s_l, k + u, 64);
            ee[u] = __shfl(ea_l, k + u, 64);
        }
        #pragma unroll
        for (int u = 0; u < 8; ++u)
            hv[u] = *(const uint*)(hn + (size_t)ss[u] * DIM + d0);
        #pragma unroll
        for (int u = 0; u < 8; ++u) {
            float m0 = fmaxf(bf2f((ushort)hv[u]) + fmaf(ee[u], we.x, bd.x), 0.f) + EPS_MSG;
            float m1 = fmaxf(bf2f((ushort)(hv[u] >> 16)) + fmaf(ee[u], we.y, bd.y), 0.f) + EPS_MSG;
            float x0 = __expf(m0 * t), x1 = __expf(m1 * t);
            den0 += x0; num0 += m0 * x0; den1 += x1; num1 += m1 * x1;
        }
    }
    for (; k < kmax; ++k) {
        int s = __shfl(s_l, k, 64);
        float ea = __shfl(ea_l, k, 64);
        uint hv = *(const uint*)(hn + (size_t)s * DIM + d0);
        float m0 = fmaxf(bf2f((ushort)hv) + fmaf(ea, we.x, bd.x), 0.f) + EPS_MSG;
        float m1 = fmaxf(bf2f((ushort)(hv >> 16)) + fmaf(ea, we.y, bd.y), 0.f) + EPS_MSG;
        float x0 = __expf(m0 * t), x1 = __expf(m1 * t);
        den0 += x0; num0 += m0 * x0; den1 += x1; num1 += m1 * x1;
    }
    for (int p = p0 + 64; p < p1; ++p) {  // rare: deg > 64
        int4 r = erec[p];
        int s = r.x;
        float ea = __int_as_float(r.z);
        uint hv = *(const uint*)(hn + (size_t)s * DIM + d0);
        float m0 = fmaxf(bf2f((ushort)hv) + fmaf(ea, we.x, bd.x), 0.f) + EPS_MSG;
        float m1 = fmaxf(bf2f((ushort)(hv >> 16)) + fmaf(ea, we.y, bd.y), 0.f) + EPS_MSG;
        float x0 = __expf(m0 * t), x1 = __expf(m1 * t);
        den0 += x0; num0 += m0 * x0; den1 += x1; num1 += m1 * x1;
    }
    uint hr = *(const uint*)(hn + (size_t)n * DIM + d0);
    float a0 = (deg > 0) ? num0 / (den0 + 1e-16f) : 0.f;
    float a1 = (deg > 0) ? num1 / (den1 + 1e-16f) : 0.f;
    uint o = (uint)f2bf(a0 + bf2f((ushort)hr)) |
             ((uint)f2bf(a1 + bf2f((ushort)(hr >> 16))) << 16);
    *(uint*)(ob + (size_t)n * DIM + d0) = o;
}

// ======== GEMM1 + bias + LayerNorm + ReLU -> bf16 z. Wave-independent, barrier-free. ====
// Each wave owns 16 rows: full 16x256 GEMM1 (K=128) + wave-local LN (z-row lives in the
// 16-lane l15 group -> 4 shfl_xor). No LDS, no __syncthreads. 3128 waves.
__global__ __launch_bounds__(256, 2) void k_g1(const ushort* __restrict__ A,
                                               const ushort* __restrict__ B1t,
                                               const float* __restrict__ b1,
                                               const float* __restrict__ g,
                                               const float* __restrict__ bv,
                                               ushort* __restrict__ Z) {
    int wv = (blockIdx.x * blockDim.x + threadIdx.x) >> 6;
    int lane = threadIdx.x & 63;
    int l15 = lane & 15, lq = lane >> 4;
    int row0 = wv * 16;

    short8v afr[4];
    #pragma unroll
    for (int ks = 0; ks < 4; ++ks)
        afr[ks] = *(const short8v*)(A + (size_t)(row0 + l15) * DIM + ks * 32 + lq * 8);

    float bb[16], gg[16], lb[16];
    #pragma unroll
    for (int nf = 0; nf < 16; ++nf) {
        int col = nf * 16 + l15;
        bb[nf] = b1[col]; gg[nf] = g[col]; lb[nf] = bv[col];
    }

    f32x4 acc[16] = {};
    #pragma unroll
    for (int nf = 0; nf < 16; ++nf) {
        short8v bfr[4];
        #pragma unroll
        for (int ks = 0; ks < 4; ++ks)
            bfr[ks] = *(const short8v*)(B1t + (size_t)(nf * 16 + l15) * DIM + ks * 32 + lq * 8);
        #pragma unroll
        for (int ks = 0; ks < 4; ++ks)
            acc[nf] = __builtin_amdgcn_mfma_f32_16x16x32_bf16(afr[ks], bfr[ks], acc[nf],
                                                              0, 0, 0);
    }

    #pragma unroll
    for (int j = 0; j < 4; ++j) {
        float s = 0.f, q = 0.f;
        #pragma unroll
        for (int nf = 0; nf < 16; ++nf) {
            float v = acc[nf][j] + bb[nf];
            acc[nf][j] = v;
            s += v; q += v * v;
        }
        #pragma unroll
        for (int off = 1; off <= 8; off <<= 1) {
            s += __shfl_xor(s, off, 64);
            q += __shfl_xor(q, off, 64);
        }
        float mu = s * (1.f / HID);
        float var = q * (1.f / HID) - mu * mu;
        float rs = rsqrtf(var + EPS_NORM);
        size_t rbase = (size_t)(row0 + lq * 4 + j) * HID;
        #pragma unroll
        for (int nf = 0; nf < 16; ++nf) {
            float v = fmaxf(fmaf((acc[nf][j] - mu) * rs, gg[nf], lb[nf]), 0.f);
            Z[rbase + nf * 16 + l15] = f2bf(v);
        }
    }
}

// ======== GEMM2 + residual epilogue. Wave-independent, barrier-free. ========
// Wave owns 16 rows: 16x128 (K=256). FIRST: base = x*Wn+bnb, write h fp32.
// else: base = Cin residual, write hb bf16.
template <int FIRST>
__global__ __launch_bounds__(256, 3) void k_g2(const ushort* __restrict__ Zg,
                                               const ushort* __restrict__ B2t,
                                               const float* __restrict__ b2,
                                               const float* __restrict__ x,
                                               const float* __restrict__ Wn,
                                               const float* __restrict__ bnb,
                                               const float* __restrict__ Cin,
                                               float* __restrict__ Cout,
                                               ushort* __restrict__ hb) {
    int wv = (blockIdx.x * blockDim.x + threadIdx.x) >> 6;
    int lane = threadIdx.x & 63;
    int l15 = lane & 15, lq = lane >> 4;
    int row0 = wv * 16;

    short8v af[8];
    #pragma unroll
    for (int ks = 0; ks < 8; ++ks)
        af[ks] = *(const short8v*)(Zg + (size_t)(row0 + l15) * HID + ks * 32 + lq * 8);

    float b2v[8], wnc[8], bnc[8];
    #pragma unroll
    for (int nf = 0; nf < 8; ++nf) {
        int col = nf * 16 + l15;
        b2v[nf] = b2[col];
        wnc[nf] = FIRST ? Wn[col] : 0.f;
        bnc[nf] = FIRST ? bnb[col] : 0.f;
    }

    f32x4 acc[8] = {};
    #pragma unroll
    for (int nf = 0; nf < 8; ++nf) {
        short8v bfr[8];
        #pragma unroll
        for (int ks = 0; ks < 8; ++ks)
            bfr[ks] = *(const short8v*)(B2t + (size_t)(nf * 16 + l15) * HID + ks * 32 + lq * 8);
        #pragma unroll
        for (int ks = 0; ks < 8; ++ks)
            acc[nf] = __builtin_amdgcn_mfma_f32_16x16x32_bf16(af[ks], bfr[ks], acc[nf],
                                                              0, 0, 0);
    }

    #pragma unroll
    for (int j = 0; j < 4; ++j) {
        int gr = row0 + lq * 4 + j;
        float xb = 0.f;
        if (FIRST) xb = (gr < NN) ? x[gr] : 0.f;
        size_t rbase = (size_t)gr * DIM;
        #pragma unroll
        for (int nf = 0; nf < 8; ++nf) {
            int col = nf * 16 + l15;
            float base = FIRST ? fmaf(xb, wnc[nf], bnc[nf]) : Cin[rbase + col];
            float v = acc[nf][j] + b2v[nf] + base;
            if (FIRST) Cout[rbase + col] = v;
            else hb[rbase + col] = f2bf(v);
        }
    }
}

// ------- dot predictor, CSR order: wave per node, 4 edges/iter (16 lanes x 8 ch) -------
__global__ __launch_bounds__(256) void k_dot(const ushort* __restrict__ hb,
                                             const int4* __restrict__ erec,
                                             const int* __restrict__ row_off,
                                             float* __restrict__ out, int N) {
    int n = blockIdx.x * 4 + (threadIdx.x >> 6);
    if (n >= N) return;
    int lane = threadIdx.x & 63;
    int sub = lane >> 4;
    int l16 = lane & 15;
    float hd[8];
    {
        ushort8v hv = *(const ushort8v*)(hb + (size_t)n * DIM + l16 * 8);
        #pragma unroll
        for (int j = 0; j < 8; ++j) hd[j] = bf2f(hv[j]);
    }
    int p0 = row_off[n], p1 = row_off[n + 1];
    int deg = p1 - p0;
    int mp = p0 + lane;
    int s_l = 0, e_l = 0;
    if (mp < p1) {
        int4 r = erec[mp];
        s_l = r.x; e_l = r.y;
    }
    int kmax = deg < 64 ? deg : 64;
    for (int k = 0; k < kmax; k += 4) {
        int idx = k + sub;
        bool ok = idx < kmax;
        int s = __shfl(s_l, idx, 64);
        int e = __shfl(e_l, idx, 64);
        ushort8v av = *(const ushort8v*)(hb + (size_t)(ok ? s : n) * DIM + l16 * 8);
        float p = 0.f;
        #pragma unroll
        for (int j = 0; j < 8; ++j) p = fmaf(bf2f(av[j]), hd[j], p);
        p += __shfl_xor(p, 1, 16);
        p += __shfl_xor(p, 2, 16);
        p += __shfl_xor(p, 4, 16);
        p += __shfl_xor(p, 8, 16);
        if (ok && l16 == 0) out[e] = p;
    }
    for (int pb = p0 + 64; pb < p1; pb += 4) {  // rare: deg > 64
        int pe = pb + sub;
        bool ok = pe < p1;
        int s = n, e = 0;
        if (ok) { int4 r = erec[pe]; s = r.x; e = r.y; }
        ushort8v av = *(const ushort8v*)(hb + (size_t)s * DIM + l16 * 8);
        float p = 0.f;
        #pragma unroll
        for (int j = 0; j < 8; ++j) p = fmaf(bf2f(av[j]), hd[j], p);
        p += __shfl_xor(p, 1, 16);
        p += __shfl_xor(p, 2, 16);
        p += __shfl_xor(p, 4, 16);
        p += __shfl_xor(p, 8, 16);
        if (ok && l16 == 0) out[e] = p;
    }
}

extern "C" void kernel_launch(void* const* d_in, const int* in_sizes, int n_in,
                              void* d_out, int out_size, void* d_ws, size_t ws_size,
                              hipStream_t stream) {
    const float* x        = (const float*)d_in[0];
    const int*   ei       = (const int*)d_in[1];
    const float* eattr    = (const float*)d_in[2];
    const float* Wn       = (const float*)d_in[3];
    const float* bnb      = (const float*)d_in[4];
    const float* We       = (const float*)d_in[5];
    const float* be       = (const float*)d_in[6];
    const float* bn_gamma = (const float*)d_in[7];
    const float* bn_beta  = (const float*)d_in[8];
    const float* t_all    = (const float*)d_in[9];
    const float* W1       = (const float*)d_in[10];
    const float* b1       = (const float*)d_in[11];
    const float* ln_g     = (const float*)d_in[12];
    const float* ln_b     = (const float*)d_in[13];
    const float* W2       = (const float*)d_in[14];
    const float* b2       = (const float*)d_in[15];
    float* out = (float*)d_out;

    const int N = NN, E = NE, D = DIM, H = HID;
    const int* src = ei;
    const int* dst = ei + E;

    char* ws = (char*)d_ws;
    auto alloc = [&](size_t bytes) {
        char* p = ws;
        ws += (bytes + 255) & ~(size_t)255;
        return p;
    };
    float*  h       = (float*)alloc((size_t)MPAD * D * 4);
    ushort* z       = (ushort*)alloc((size_t)MPAD * H * 2);
    ushort* ob      = (ushort*)alloc((size_t)MPAD * D * 2);
    ushort* hn      = (ushort*)alloc((size_t)MPAD * D * 2);
    ushort* hb      = (ushort*)alloc((size_t)MPAD * D * 2);
    ushort* W1t     = (ushort*)alloc((size_t)2 * D * H * 2);
    ushort* W2t     = (ushort*)alloc((size_t)2 * D * H * 2);
    int4*   erec    = (int4*)alloc((size_t)E * 16);
    int*    row_off = (int*)alloc((size_t)(N + 1) * 4);
    int*    cursor  = (int*)alloc((size_t)N * 4);
    int*    deg     = (int*)alloc((size_t)N * 4);
    int*    partials= (int*)alloc((size_t)64 * 4);
    int*    pbase   = (int*)alloc((size_t)64 * 4);
    float*  stats   = (float*)alloc((size_t)2 * D * 4);   // 1024 B
    float*  xs      = (float*)alloc((size_t)2 * 4);       // adjacent: one memset covers

    hipMemsetAsync(deg, 0, (size_t)N * 4, stream);
    hipMemsetAsync(stats, 0, 1024 + 8, stream);

    k_setup<<<64 + HIST_BLOCKS + CAST_BLOCKS, 256, 0, stream>>>(x, dst, W1, W2,
                                                                xs, deg, W1t, W2t);
    k_scanA<<<NB, 256, 0, stream>>>(deg, partials, N);
    k_scanB<<<1, 64, 0, stream>>>(partials, pbase, row_off);
    k_scanC<<<NB, 1024, 0, stream>>>(deg, pbase, row_off, cursor, N);
    k_scatter<<<(E + 255) / 256, 256, 0, stream>>>(src, dst, eattr, cursor, erec, E);
    k_hn0<<<(N * 32 + 255) / 256, 256, 0, stream>>>(x, xs, Wn, bnb, bn_gamma, bn_beta,
                                                    hn, N * 32);

    // ---- layer 0 ----
    k_agg<<<(N + 3) / 4, 256, 0, stream>>>(hn, erec, row_off, We, be, t_all, 0, ob, N);
    k_g1<<<NW16 / 4, 256, 0, stream>>>(ob, W1t, b1, ln_g, ln_b, z);
    k_g2<1><<<NW16 / 4, 256, 0, stream>>>(z, W2t, b2, x, Wn, bnb, h, h, hb);
    k_bn_stats<<<256, 256, 0, stream>>>(h, stats);
    k_bn_relu<<<(N * 32 + 255) / 256, 256, 0, stream>>>(h, stats, bn_gamma + D, bn_beta + D,
                                                        hn, N * 32);

    // ---- layer 1 ----
    k_agg<<<(N + 3) / 4, 256, 0, stream>>>(hn, erec, row_off, We, be, t_all, 1, ob, N);
    k_g1<<<NW16 / 4, 256, 0, stream>>>(ob, W1t + (size_t)D * H, b1 + H,
                                       ln_g + H, ln_b + H, z);
    k_g2<0><<<NW16 / 4, 256, 0, stream>>>(z, W2t + (size_t)D * H, b2 + D,
                                          x, Wn, bnb, h, h, hb);

    k_dot<<<(N + 3) / 4, 256, 0, stream>>>(hb, erec, row_off, out, N);
}

// Round 10
// 396.431 us; speedup vs baseline: 1.1837x; 1.1837x over previous
//
#include <hip/hip_runtime.h>
#include <hip/hip_bf16.h>
#include <math.h>

#define NN 50000
#define NE 600000
#define MPAD 50048      // 1564*32
#define NS32 (MPAD / 32)
#define DIM 128
#define HID 256
#define NB 49           // ceil(NN/1024)
#define HIST_BLOCKS ((NE + 255) / 256)
#define CAST_BLOCKS ((4 * DIM * HID) / 256)
#define EPS_MSG 1e-7f
#define EPS_NORM 1e-5f

typedef __attribute__((ext_vector_type(8))) short short8v;
typedef __attribute__((ext_vector_type(8))) unsigned short ushort8v;
typedef __attribute__((ext_vector_type(4))) float f32x4;

__device__ inline ushort f2bf(float f) {
    union { float f; unsigned u; } v; v.f = f;
    unsigned r = v.u + 0x7FFF + ((v.u >> 16) & 1);
    return (ushort)(r >> 16);
}
__device__ inline float bf2f(ushort u) {
    union { unsigned u; float f; } v; v.u = (unsigned)u << 16; return v.f;
}

// ---- fused setup: blocks [0,64) xstats | [64,64+HIST) hist | rest weight cast+T ----
__global__ __launch_bounds__(256) void k_setup(const float* __restrict__ x,
                                               const int* __restrict__ dst,
                                               const float* __restrict__ W1,
                                               const float* __restrict__ W2,
                                               float* __restrict__ xs,
                                               int* __restrict__ deg,
                                               ushort* __restrict__ W1t,
                                               ushort* __restrict__ W2t) {
    int b = blockIdx.x;
    if (b < 64) {
        int lane = threadIdx.x & 63;
        float s = 0.f, q = 0.f;
        for (int i = b * 256 + threadIdx.x; i < NN; i += 64 * 256) {
            float v = x[i];
            s += v; q += v * v;
        }
        #pragma unroll
        for (int off = 32; off >= 1; off >>= 1) {
            s += __shfl_xor(s, off, 64);
            q += __shfl_xor(q, off, 64);
        }
        if (lane == 0) { atomicAdd(&xs[0], s); atomicAdd(&xs[1], q); }
    } else if (b < 64 + HIST_BLOCKS) {
        int i = (b - 64) * 256 + threadIdx.x;
        if (i < NE) atomicAdd(&deg[dst[i]], 1);
    } else {
        const int chunk = DIM * HID;
        int i = (b - 64 - HIST_BLOCKS) * 256 + threadIdx.x;
        int w = i / chunk;
        int j = i - w * chunk;
        if (w < 2) {
            int r = j / HID, c = j - r * HID;
            W1t[(size_t)w * chunk + (size_t)c * DIM + r] = f2bf(W1[(size_t)w * chunk + j]);
        } else {
            int l = w - 2;
            int r = j / DIM, c = j - r * DIM;
            W2t[(size_t)l * chunk + (size_t)c * HID + r] = f2bf(W2[(size_t)l * chunk + j]);
        }
    }
}

// ------- layer-0 hn (bf16): BN params in closed form (h = x*Wn + bnb is rank-1) -------
__global__ void k_hn0(const float* __restrict__ x, const float* __restrict__ xs,
                      const float* __restrict__ Wn, const float* __restrict__ bnb,
                      const float* __restrict__ gamma, const float* __restrict__ beta,
                      ushort* __restrict__ hn, int total4) {
    int i = blockIdx.x * blockDim.x + threadIdx.x;
    if (i >= total4) return;
    int d4 = (i & 31) * 4;
    int n = i >> 5;
    float mx = xs[0] * (1.f / NN);
    float vx = xs[1] * (1.f / NN) - mx * mx;
    float xv = x[n];
    float4 w = *(const float4*)(Wn + d4);
    float4 b = *(const float4*)(bnb + d4);
    float4 g = *(const float4*)(gamma + d4);
    float4 bt = *(const float4*)(beta + d4);
    ushort4 o;
    {
        float mu = fmaf(mx, w.x, b.x), sc = rsqrtf(vx * w.x * w.x + EPS_NORM) * g.x;
        o.x = f2bf(fmaxf(fmaf(fmaf(xv, w.x, b.x) - mu, sc, bt.x), 0.f));
    }
    {
        float mu = fmaf(mx, w.y, b.y), sc = rsqrtf(vx * w.y * w.y + EPS_NORM) * g.y;
        o.y = f2bf(fmaxf(fmaf(fmaf(xv, w.y, b.y) - mu, sc, bt.y), 0.f));
    }
    {
        float mu = fmaf(mx, w.z, b.z), sc = rsqrtf(vx * w.z * w.z + EPS_NORM) * g.z;
        o.z = f2bf(fmaxf(fmaf(fmaf(xv, w.z, b.z) - mu, sc, bt.z), 0.f));
    }
    {
        float mu = fmaf(mx, w.w, b.w), sc = rsqrtf(vx * w.w * w.w + EPS_NORM) * g.w;
        o.w = f2bf(fmaxf(fmaf(fmaf(xv, w.w, b.w) - mu, sc, bt.w), 0.f));
    }
    *(ushort4*)(hn + (size_t)n * DIM + d4) = o;
}

// ---------------- CSR build (multi-block scan) ----------------
__global__ __launch_bounds__(256) void k_scanA(const int* __restrict__ deg,
                                               int* __restrict__ partials, int n) {
    __shared__ int ws[4];
    int b = blockIdx.x;
    int t = threadIdx.x;
    int s = 0;
    #pragma unroll
    for (int i = 0; i < 4; ++i) {
        int idx = b * 1024 + t + i * 256;
        s += (idx < n) ? deg[idx] : 0;
    }
    #pragma unroll
    for (int off = 32; off >= 1; off >>= 1) s += __shfl_xor(s, off, 64);
    if ((t & 63) == 0) ws[t >> 6] = s;
    __syncthreads();
    if (t == 0) partials[b] = ws[0] + ws[1] + ws[2] + ws[3];
}

__global__ __launch_bounds__(64) void k_scanB(const int* __restrict__ partials,
                                              int* __restrict__ base,
                                              int* __restrict__ row_off) {
    int t = threadIdx.x;
    int v = (t < NB) ? partials[t] : 0;
    int x = v;
    #pragma unroll
    for (int off = 1; off < 64; off <<= 1) {
        int y = __shfl_up(x, off, 64);
        if (t >= off) x += y;
    }
    if (t < NB) base[t] = x - v;
    if (t == 0) row_off[NN] = NE;
}

__global__ __launch_bounds__(1024) void k_scanC(const int* __restrict__ deg,
                                                const int* __restrict__ base,
                                                int* __restrict__ row_off,
                                                int* __restrict__ cursor, int n) {
    __shared__ int wsum[16];
    int i = blockIdx.x * 1024 + threadIdx.x;
    int lane = threadIdx.x & 63;
    int wid = threadIdx.x >> 6;
    int v = (i < n) ? deg[i] : 0;
    int x = v;
    #pragma unroll
    for (int off = 1; off < 64; off <<= 1) {
        int y = __shfl_up(x, off, 64);
        if (lane >= off) x += y;
    }
    if (lane == 63) wsum[wid] = x;
    __syncthreads();
    if (wid == 0 && lane < 16) {
        int w = wsum[lane];
        #pragma unroll
        for (int off = 1; off < 16; off <<= 1) {
            int y = __shfl_up(w, off, 64);
            if (lane >= off) w += y;
        }
        wsum[lane] = w;
    }
    __syncthreads();
    int prev = (wid == 0) ? 0 : wsum[wid - 1];
    int excl = base[blockIdx.x] + prev + (x - v);
    if (i < n) { row_off[i] = excl; cursor[i] = excl; }
}

// scatter packed edge record: src(16b) | eid(20b) | ea-bf16(16b) -> one 8B store
__global__ void k_scatter(const int* __restrict__ src, const int* __restrict__ dst,
                          const float* __restrict__ eattr, int* __restrict__ cursor,
                          unsigned long long* __restrict__ erec, int E) {
    int i = blockIdx.x * blockDim.x + threadIdx.x;
    if (i >= E) return;
    int d = dst[i];
    int pos = atomicAdd(&cursor[d], 1);
    unsigned long long r = (unsigned long long)(unsigned)src[i]
                         | ((unsigned long long)(unsigned)i << 16)
                         | ((unsigned long long)f2bf(eattr[i]) << 36);
    erec[pos] = r;
}

// ------- BN column stats over h (fp32): grid-stride, per-thread accumulate -------
__global__ __launch_bounds__(256) void k_bn_stats(const float* __restrict__ h,
                                                  float* __restrict__ stats) {
    __shared__ float red[2][128];
    int d = threadIdx.x & 127;
    int rsub = threadIdx.x >> 7;
    float s = 0.f, q = 0.f;
    for (int r = blockIdx.x * 2 + rsub; r < NN; r += gridDim.x * 2) {
        float v = h[(size_t)r * DIM + d];
        s += v; q += v * v;
    }
    if (rsub == 0) { red[0][d] = s; red[1][d] = q; }
    __syncthreads();
    if (rsub == 1) {
        atomicAdd(&stats[d], s + red[0][d]);
        atomicAdd(&stats[DIM + d], q + red[1][d]);
    }
}

// ------- BN apply + ReLU -> bf16 hn (finalize fused per-thread from raw stats) -------
__global__ void k_bn_relu(const float* __restrict__ h, const float* __restrict__ stats,
                          const float* __restrict__ gamma, const float* __restrict__ beta,
                          ushort* __restrict__ hn, int total4) {
    int i = blockIdx.x * blockDim.x + threadIdx.x;
    if (i >= total4) return;
    int d4 = (i & 31) * 4;
    int n = i >> 5;
    float4 v = *(const float4*)(h + (size_t)n * DIM + d4);
    float4 s = *(const float4*)(stats + d4);
    float4 q = *(const float4*)(stats + DIM + d4);
    float4 g = *(const float4*)(gamma + d4);
    float4 bt = *(const float4*)(beta + d4);
    ushort4 o;
    {
        float mu = s.x * (1.f / NN), var = q.x * (1.f / NN) - mu * mu;
        float sc = rsqrtf(var + EPS_NORM) * g.x;
        o.x = f2bf(fmaxf(fmaf(v.x - mu, sc, bt.x), 0.f));
    }
    {
        float mu = s.y * (1.f / NN), var = q.y * (1.f / NN) - mu * mu;
        float sc = rsqrtf(var + EPS_NORM) * g.y;
        o.y = f2bf(fmaxf(fmaf(v.y - mu, sc, bt.y), 0.f));
    }
    {
        float mu = s.z * (1.f / NN), var = q.z * (1.f / NN) - mu * mu;
        float sc = rsqrtf(var + EPS_NORM) * g.z;
        o.z = f2bf(fmaxf(fmaf(v.z - mu, sc, bt.z), 0.f));
    }
    {
        float mu = s.w * (1.f / NN), var = q.w * (1.f / NN) - mu * mu;
        float sc = rsqrtf(var + EPS_NORM) * g.w;
        o.w = f2bf(fmaxf(fmaf(v.w - mu, sc, bt.w), 0.f));
    }
    *(ushort4*)(hn + (size_t)n * DIM + d4) = o;
}

// ------- GENConv softmax aggregation: wave per node, lane = 2 channels, unroll-8 -------
__global__ __launch_bounds__(256) void k_agg(const ushort* __restrict__ hn,
                                             const unsigned long long* __restrict__ erec,
                                             const int* __restrict__ row_off,
                                             const float* __restrict__ We,
                                             const float* __restrict__ be,
                                             const float* __restrict__ t_all, int l,
                                             ushort* __restrict__ ob, int N) {
    int n = blockIdx.x * 4 + (threadIdx.x >> 6);
    if (n >= N) return;
    int lane = threadIdx.x & 63;
    int d0 = lane * 2;
    float2 we = *(const float2*)(We + d0);
    float2 bd = *(const float2*)(be + d0);
    float t = t_all[l];
    int p0 = row_off[n], p1 = row_off[n + 1];
    int deg = p1 - p0;

    int mp = p0 + lane;
    unsigned long long r_l = (mp < p1) ? erec[mp] : 0ull;

    float den0 = 0.f, num0 = 0.f, den1 = 0.f, num1 = 0.f;
    int kmax = deg < 64 ? deg : 64;
    int k = 0;
    for (; k + 8 <= kmax; k += 8) {
        int ss[8]; float ee[8]; uint hv[8];
        #pragma unroll
        for (int u = 0; u < 8; ++u) {
            unsigned long long r = __shfl(r_l, k + u, 64);
            ss[u] = (int)(r & 0xFFFF);
            ee[u] = bf2f((ushort)(r >> 36));
        }
        #pragma unroll
        for (int u = 0; u < 8; ++u)
            hv[u] = *(const uint*)(hn + (size_t)ss[u] * DIM + d0);
        #pragma unroll
        for (int u = 0; u < 8; ++u) {
            float m0 = fmaxf(bf2f((ushort)hv[u]) + fmaf(ee[u], we.x, bd.x), 0.f) + EPS_MSG;
            float m1 = fmaxf(bf2f((ushort)(hv[u] >> 16)) + fmaf(ee[u], we.y, bd.y), 0.f) + EPS_MSG;
            float x0 = __expf(m0 * t), x1 = __expf(m1 * t);
            den0 += x0; num0 += m0 * x0; den1 += x1; num1 += m1 * x1;
        }
    }
    for (; k < kmax; ++k) {
        unsigned long long r = __shfl(r_l, k, 64);
        int s = (int)(r & 0xFFFF);
        float ea = bf2f((ushort)(r >> 36));
        uint hv = *(const uint*)(hn + (size_t)s * DIM + d0);
        float m0 = fmaxf(bf2f((ushort)hv) + fmaf(ea, we.x, bd.x), 0.f) + EPS_MSG;
        float m1 = fmaxf(bf2f((ushort)(hv >> 16)) + fmaf(ea, we.y, bd.y), 0.f) + EPS_MSG;
        float x0 = __expf(m0 * t), x1 = __expf(m1 * t);
        den0 += x0; num0 += m0 * x0; den1 += x1; num1 += m1 * x1;
    }
    for (int p = p0 + 64; p < p1; ++p) {  // rare: deg > 64
        unsigned long long r = erec[p];
        int s = (int)(r & 0xFFFF);
        float ea = bf2f((ushort)(r >> 36));
        uint hv = *(const uint*)(hn + (size_t)s * DIM + d0);
        float m0 = fmaxf(bf2f((ushort)hv) + fmaf(ea, we.x, bd.x), 0.f) + EPS_MSG;
        float m1 = fmaxf(bf2f((ushort)(hv >> 16)) + fmaf(ea, we.y, bd.y), 0.f) + EPS_MSG;
        float x0 = __expf(m0 * t), x1 = __expf(m1 * t);
        den0 += x0; num0 += m0 * x0; den1 += x1; num1 += m1 * x1;
    }
    uint hr = *(const uint*)(hn + (size_t)n * DIM + d0);
    float a0 = (deg > 0) ? num0 / (den0 + 1e-16f) : 0.f;
    float a1 = (deg > 0) ? num1 / (den1 + 1e-16f) : 0.f;
    uint o = (uint)f2bf(a0 + bf2f((ushort)hr)) |
             ((uint)f2bf(a1 + bf2f((ushort)(hr >> 16))) << 16);
    *(uint*)(ob + (size_t)n * DIM + d0) = o;
}

// ======== fused MLP: LDS-resident weights + wave-independent compute, no steady barriers.
// 256 blocks x 4 waves; W1/W2 staged once (132.6 KB). Each wave owns 32-row strips:
// GEMM1(B from LDS) -> wave-local LN -> z to global bf16 -> vmcnt(0) -> GEMM2 A readback
// (memory round-trip = transpose; z is L2-hot) -> GEMM2(B from LDS) -> epilogue.
template <int FIRST>
__global__ __launch_bounds__(256, 1) void k_mlpw(const ushort* __restrict__ A,
                                                 const ushort* __restrict__ B1t,
                                                 const float* __restrict__ b1,
                                                 const float* __restrict__ g,
                                                 const float* __restrict__ bv,
                                                 const ushort* __restrict__ B2t,
                                                 const float* __restrict__ b2,
                                                 const float* __restrict__ x,
                                                 const float* __restrict__ Wn,
                                                 const float* __restrict__ bnb,
                                                 const float* __restrict__ Cin,
                                                 float* __restrict__ Cout,
                                                 ushort* __restrict__ hb,
                                                 ushort* Z) {
    constexpr int LW1 = 130;  // 65 dwords/row, gcd(65,32)=1 -> spread banks
    constexpr int LW2 = 258;  // 129 dwords/row, gcd=1
    __shared__ ushort W1s[256 * LW1];  // 66560 B
    __shared__ ushort W2s[128 * LW2];  // 66048 B
    const int tid = threadIdx.x;
    const int lane = tid & 63;
    const int wid = tid >> 6;
    const int l15 = lane & 15;
    const int lq = lane >> 4;

    #pragma unroll
    for (int i = 0; i < 16; ++i) {
        int e = (tid + i * 256) * 8;
        int r = e >> 7, c = e & 127;
        *(short8v*)(W1s + r * LW1 + c) = *(const short8v*)(B1t + r * 128 + c);
    }
    #pragma unroll
    for (int i = 0; i < 16; ++i) {
        int e = (tid + i * 256) * 8;
        int r = e >> 8, c = e & 255;
        *(short8v*)(W2s + r * LW2 + c) = *(const short8v*)(B2t + r * 256 + c);
    }
    float bb[16], gg[16], lb[16];
    #pragma unroll
    for (int nf = 0; nf < 16; ++nf) {
        int col = nf * 16 + l15;
        bb[nf] = b1[col]; gg[nf] = g[col]; lb[nf] = bv[col];
    }
    float b2v[8], wnc[8], bnc[8];
    #pragma unroll
    for (int nf = 0; nf < 8; ++nf) {
        int col = nf * 16 + l15;
        b2v[nf] = b2[col];
        wnc[nf] = FIRST ? Wn[col] : 0.f;
        bnc[nf] = FIRST ? bnb[col] : 0.f;
    }
    __syncthreads();  // weights staged; no barriers after this point

    for (int s = blockIdx.x * 4 + wid; s < NS32; s += 1024) {
        const int row0 = s * 32;
        // ---- A fragments: 32 rows, K=128 ----
        short8v afr[4][2];
        #pragma unroll
        for (int ks = 0; ks < 4; ++ks)
            #pragma unroll
            for (int mi = 0; mi < 2; ++mi)
                afr[ks][mi] = *(const short8v*)(A + (size_t)(row0 + mi * 16 + l15) * DIM +
                                                ks * 32 + lq * 8);
        // ---- GEMM1: 32 x 256, K=128 ----
        f32x4 acc[16][2] = {};
        #pragma unroll
        for (int ks = 0; ks < 4; ++ks) {
            int kk = ks * 32 + lq * 8;
            #pragma unroll
            for (int nf = 0; nf < 16; ++nf) {
                short8v bfr = *(const short8v*)(W1s + (nf * 16 + l15) * LW1 + kk);
                #pragma unroll
                for (int mi = 0; mi < 2; ++mi)
                    acc[nf][mi] = __builtin_amdgcn_mfma_f32_16x16x32_bf16(
                        afr[ks][mi], bfr, acc[nf][mi], 0, 0, 0);
            }
        }
        // ---- bias + wave-local LN (row = mi*16+lq*4+j; cols on nf,l15) + z out ----
        #pragma unroll
        for (int mi = 0; mi < 2; ++mi) {
            #pragma unroll
            for (int j = 0; j < 4; ++j) {
                float sum = 0.f, sq = 0.f;
                #pragma unroll
                for (int nf = 0; nf < 16; ++nf) {
                    float v = acc[nf][mi][j] + bb[nf];
                    acc[nf][mi][j] = v;
                    sum += v; sq += v * v;
                }
                #pragma unroll
                for (int off = 1; off <= 8; off <<= 1) {
                    sum += __shfl_xor(sum, off, 64);
                    sq += __shfl_xor(sq, off, 64);
                }
                float mu = sum * (1.f / HID);
                float var = sq * (1.f / HID) - mu * mu;
                float rs = rsqrtf(var + EPS_NORM);
                size_t rbase = (size_t)(row0 + mi * 16 + lq * 4 + j) * HID;
                #pragma unroll
                for (int nf = 0; nf < 16; ++nf) {
                    float v = fmaxf(fmaf((acc[nf][mi][j] - mu) * rs, gg[nf], lb[nf]), 0.f);
                    Z[rbase + nf * 16 + l15] = f2bf(v);
                }
            }
        }
        asm volatile("s_waitcnt vmcnt(0)" ::: "memory");  // z visible for readback
        // ---- GEMM2: 32 x 128, K=256. A = z readback (transposed via memory). ----
        short8v af2[2][8];
        #pragma unroll
        for (int mi = 0; mi < 2; ++mi)
            #pragma unroll
            for (int ks = 0; ks < 8; ++ks)
                af2[mi][ks] = *(const short8v*)(Z + (size_t)(row0 + mi * 16 + l15) * HID +
                                                ks * 32 + lq * 8);
        f32x4 acc2[8][2] = {};
        #pragma unroll
        for (int ks = 0; ks < 8; ++ks) {
            int kk = ks * 32 + lq * 8;
            #pragma unroll
            for (int nf = 0; nf < 8; ++nf) {
                short8v bf2 = *(const short8v*)(W2s + (nf * 16 + l15) * LW2 + kk);
                #pragma unroll
                for (int mi = 0; mi < 2; ++mi)
                    acc2[nf][mi] = __builtin_amdgcn_mfma_f32_16x16x32_bf16(
                        af2[mi][ks], bf2, acc2[nf][mi], 0, 0, 0);
            }
        }
        // ---- epilogue ----
        #pragma unroll
        for (int mi = 0; mi < 2; ++mi) {
            #pragma unroll
            for (int j = 0; j < 4; ++j) {
                int gr = row0 + mi * 16 + lq * 4 + j;
                float xb = 0.f;
                if (FIRST) xb = (gr < NN) ? x[gr] : 0.f;
                size_t rbase = (size_t)gr * DIM;
                #pragma unroll
                for (int nf = 0; nf < 8; ++nf) {
                    int col = nf * 16 + l15;
                    float base = FIRST ? fmaf(xb, wnc[nf], bnc[nf]) : Cin[rbase + col];
                    float v = acc2[nf][mi][j] + b2v[nf] + base;
                    if (FIRST) Cout[rbase + col] = v;
                    else hb[rbase + col] = f2bf(v);
                }
            }
        }
    }
}

// ------- dot predictor, CSR order: wave per node, 4 edges/iter (16 lanes x 8 ch) -------
__global__ __launch_bounds__(256) void k_dot(const ushort* __restrict__ hb,
                                             const unsigned long long* __restrict__ erec,
                                             const int* __restrict__ row_off,
                                             float* __restrict__ out, int N) {
    int n = blockIdx.x * 4 + (threadIdx.x >> 6);
    if (n >= N) return;
    int lane = threadIdx.x & 63;
    int sub = lane >> 4;
    int l16 = lane & 15;
    float hd[8];
    {
        ushort8v hv = *(const ushort8v*)(hb + (size_t)n * DIM + l16 * 8);
        #pragma unroll
        for (int j = 0; j < 8; ++j) hd[j] = bf2f(hv[j]);
    }
    int p0 = row_off[n], p1 = row_off[n + 1];
    int deg = p1 - p0;
    int mp = p0 + lane;
    unsigned long long r_l = (mp < p1) ? erec[mp] : 0ull;
    int kmax = deg < 64 ? deg : 64;
    for (int k = 0; k < kmax; k += 4) {
        int idx = k + sub;
        bool ok = idx < kmax;
        unsigned long long r = __shfl(r_l, idx, 64);
        int s = (int)(r & 0xFFFF);
        int e = (int)((r >> 16) & 0xFFFFF);
        ushort8v av = *(const ushort8v*)(hb + (size_t)(ok ? s : n) * DIM + l16 * 8);
        float p = 0.f;
        #pragma unroll
        for (int j = 0; j < 8; ++j) p = fmaf(bf2f(av[j]), hd[j], p);
        p += __shfl_xor(p, 1, 16);
        p += __shfl_xor(p, 2, 16);
        p += __shfl_xor(p, 4, 16);
        p += __shfl_xor(p, 8, 16);
        if (ok && l16 == 0) out[e] = p;
    }
    for (int pb = p0 + 64; pb < p1; pb += 4) {  // rare: deg > 64
        int pe = pb + sub;
        bool ok = pe < p1;
        int s = n, e = 0;
        if (ok) {
            unsigned long long r = erec[pe];
            s = (int)(r & 0xFFFF);
            e = (int)((r >> 16) & 0xFFFFF);
        }
        ushort8v av = *(const ushort8v*)(hb + (size_t)s * DIM + l16 * 8);
        float p = 0.f;
        #pragma unroll
        for (int j = 0; j < 8; ++j) p = fmaf(bf2f(av[j]), hd[j], p);
        p += __shfl_xor(p, 1, 16);
        p += __shfl_xor(p, 2, 16);
        p += __shfl_xor(p, 4, 16);
        p += __shfl_xor(p, 8, 16);
        if (ok && l16 == 0) out[e] = p;
    }
}

extern "C" void kernel_launch(void* const* d_in, const int* in_sizes, int n_in,
                              void* d_out, int out_size, void* d_ws, size_t ws_size,
                              hipStream_t stream) {
    const float* x        = (const float*)d_in[0];
    const int*   ei       = (const int*)d_in[1];
    const float* eattr    = (const float*)d_in[2];
    const float* Wn       = (const float*)d_in[3];
    const float* bnb      = (const float*)d_in[4];
    const float* We       = (const float*)d_in[5];
    const float* be       = (const float*)d_in[6];
    const float* bn_gamma = (const float*)d_in[7];
    const float* bn_beta  = (const float*)d_in[8];
    const float* t_all    = (const float*)d_in[9];
    const float* W1       = (const float*)d_in[10];
    const float* b1       = (const float*)d_in[11];
    const float* ln_g     = (const float*)d_in[12];
    const float* ln_b     = (const float*)d_in[13];
    const float* W2       = (const float*)d_in[14];
    const float* b2       = (const float*)d_in[15];
    float* out = (float*)d_out;

    const int N = NN, E = NE, D = DIM, H = HID;
    const int* src = ei;
    const int* dst = ei + E;

    char* ws = (char*)d_ws;
    auto alloc = [&](size_t bytes) {
        char* p = ws;
        ws += (bytes + 255) & ~(size_t)255;
        return p;
    };
    float*  h       = (float*)alloc((size_t)MPAD * D * 4);
    ushort* z       = (ushort*)alloc((size_t)MPAD * H * 2);
    ushort* ob      = (ushort*)alloc((size_t)MPAD * D * 2);
    ushort* hn      = (ushort*)alloc((size_t)MPAD * D * 2);
    ushort* hb      = (ushort*)alloc((size_t)MPAD * D * 2);
    ushort* W1t     = (ushort*)alloc((size_t)2 * D * H * 2);
    ushort* W2t     = (ushort*)alloc((size_t)2 * D * H * 2);
    unsigned long long* erec = (unsigned long long*)alloc((size_t)E * 8);
    int*    row_off = (int*)alloc((size_t)(N + 1) * 4);
    int*    cursor  = (int*)alloc((size_t)N * 4);
    int*    deg     = (int*)alloc((size_t)N * 4);
    int*    partials= (int*)alloc((size_t)64 * 4);
    int*    pbase   = (int*)alloc((size_t)64 * 4);
    float*  stats   = (float*)alloc((size_t)2 * D * 4);   // 1024 B
    float*  xs      = (float*)alloc((size_t)2 * 4);       // adjacent: one memset covers

    hipMemsetAsync(deg, 0, (size_t)N * 4, stream);
    hipMemsetAsync(stats, 0, 1024 + 8, stream);

    k_setup<<<64 + HIST_BLOCKS + CAST_BLOCKS, 256, 0, stream>>>(x, dst, W1, W2,
                                                                xs, deg, W1t, W2t);
    k_scanA<<<NB, 256, 0, stream>>>(deg, partials, N);
    k_scanB<<<1, 64, 0, stream>>>(partials, pbase, row_off);
    k_scanC<<<NB, 1024, 0, stream>>>(deg, pbase, row_off, cursor, N);
    k_scatter<<<(E + 255) / 256, 256, 0, stream>>>(src, dst, eattr, cursor, erec, E);
    k_hn0<<<(N * 32 + 255) / 256, 256, 0, stream>>>(x, xs, Wn, bnb, bn_gamma, bn_beta,
                                                    hn, N * 32);

    // ---- layer 0 ----
    k_agg<<<(N + 3) / 4, 256, 0, stream>>>(hn, erec, row_off, We, be, t_all, 0, ob, N);
    k_mlpw<1><<<256, 256, 0, stream>>>(ob, W1t, b1, ln_g, ln_b, W2t, b2,
                                       x, Wn, bnb, h, h, hb, z);
    k_bn_stats<<<256, 256, 0, stream>>>(h, stats);
    k_bn_relu<<<(N * 32 + 255) / 256, 256, 0, stream>>>(h, stats, bn_gamma + D, bn_beta + D,
                                                        hn, N * 32);

    // ---- layer 1 ----
    k_agg<<<(N + 3) / 4, 256, 0, stream>>>(hn, erec, row_off, We, be, t_all, 1, ob, N);
    k_mlpw<0><<<256, 256, 0, stream>>>(ob, W1t + (size_t)D * H, b1 + H,
                                       ln_g + H, ln_b + H, W2t + (size_t)D * H, b2 + D,
                                       x, Wn, bnb, h, h, hb, z);

    k_dot<<<(N + 3) / 4, 256, 0, stream>>>(hb, erec, row_off, out, N);
}